// Round 4
// baseline (453.529 us; speedup 1.0000x reference)
//
#include <hip/hip_runtime.h>
#include <hip/hip_bf16.h>
#include <cstdint>

#define B_   8
#define T_   4096
#define D_   1024
#define M_   (B_*T_)      // 32768
#define K_   D_           // 1024
#define N_   D_           // 1024

#define TC2  64           // scan chunk length (= one wave's row span in GEMM)
#define NC2  (T_/TC2)     // 64 chunks

#define BM   256
#define BN   128
#define BK   64
#define NSTEP (K_/BK)     // 16

typedef __attribute__((ext_vector_type(8))) short  short8;
typedef __attribute__((ext_vector_type(4))) float  floatx4;

// ---- workspace layout (bytes) ----
#define XB_OFF    0ull                                   // x as bf16: 64 MiB
#define WR_OFF    (XB_OFF + (size_t)M_*K_*2)             // W_r bf16: 2 MiB
#define WI_OFF    (WR_OFF + (size_t)N_*K_*2)             // W_i bf16: 2 MiB
#define LS_OFF    (WI_OFF + (size_t)N_*K_*2)             // logsigmoid(lambd): 4 KiB
#define ASUM_OFF  (LS_OFF + (size_t)D_*4)                // chunk prod(a) -> carries: 2 MiB
#define ESUM_OFF  (ASUM_OFF + (size_t)B_*NC2*D_*4)       // chunk h_end: 2 MiB
#define WS_NEED   (ESUM_OFF + (size_t)B_*NC2*D_*4)

__device__ __forceinline__ uint32_t f2bf(float f) {
  uint32_t u = __float_as_uint(f);
  return (u + 0x7fffu + ((u >> 16) & 1u)) >> 16;   // RTNE bf16
}

__device__ __forceinline__ void gload_lds16(const void* g, void* l) {
  __builtin_amdgcn_global_load_lds(
      (const __attribute__((address_space(1))) void*)g,
      (__attribute__((address_space(3))) void*)l, 16, 0, 0);
}

#define MFMA_CLUSTER(ACC, AF, BF)                                        \
  _Pragma("unroll")                                                      \
  for (int fm = 0; fm < 4; ++fm)                                         \
    _Pragma("unroll")                                                    \
    for (int fn = 0; fn < 4; ++fn)                                       \
      ACC[fm][fn] = __builtin_amdgcn_mfma_f32_16x16x32_bf16(             \
          AF[fm], BF[fn], ACC[fm][fn], 0, 0, 0);

// ---------------- Kernel A: fp32 -> bf16 conversion + logsigmoid(lambd) ----
__global__ __launch_bounds__(256) void convert_kernel(
    const float* __restrict__ x, const float* __restrict__ wr,
    const float* __restrict__ wi, const float* __restrict__ lambd,
    uint2* __restrict__ xb, uint2* __restrict__ wrb, uint2* __restrict__ wib,
    float* __restrict__ ls) {
  int gid = blockIdx.x * 256 + threadIdx.x;
  if (gid < D_) {
    float l = lambd[gid];
    // log_sigmoid(l) = min(l,0) - log1p(exp(-|l|)), stable
    ls[gid] = fminf(l, 0.f) - log1pf(__expf(-fabsf(l)));
  }
  const int XQ = M_*K_/4;   // float4 quads in x
  const int WQ = N_*K_/4;   // quads in each W
  int stride = gridDim.x * 256;
  for (int q = gid; q < XQ + 2*WQ; q += stride) {
    const float4* src; uint2* dst; int i;
    if (q < XQ)           { src = (const float4*)x;  dst = xb;  i = q; }
    else if (q < XQ + WQ) { src = (const float4*)wr; dst = wrb; i = q - XQ; }
    else                  { src = (const float4*)wi; dst = wib; i = q - XQ - WQ; }
    float4 v = src[i];
    uint2 o;
    o.x = (f2bf(v.y) << 16) | f2bf(v.x);
    o.y = (f2bf(v.w) << 16) | f2bf(v.z);
    dst[i] = o;
  }
}

// ---------------- Kernel B: dual GEMM, 8-phase counted-vmcnt schedule -------
// BM=256 x BN=128, 8 waves (4x2 grid, per-wave 64x64 output x {R,I}).
// LDS 128 KiB: double-buffered (A 32K | Br 16K | Bi 16K) x 2. 1 block/CU.
//
// T3+T4 port (m194-m201 template): each K-tile = 4 phases of 16 MFMA:
//   p0: R,kk0 (reads A kk0 + Br kk0)   stage A-half0 of tile t+1
//   p1: I,kk0 (reads Bi kk0; af reuse) stage A-half1
//   p2: R,kk1 (reads A kk1 + Br kk1)  stage Br
//   p3: I,kk1 (reads Bi kk1; af reuse) stage Bi
// Waits are COUNTED, never a drain in the main loop:
//   end of p0: vmcnt(2)  -> completes Bi(t)   [outstanding: A-half0(t+1)]
//   end of p3: vmcnt(2)  -> completes A0/A1/Br(t+1) [outstanding: Bi(t+1)]
// Race proof: reads of buf[t&1] happen in phases of tile t; writes of that
// buffer (stage of tile t+1 -> buf[(t+1)&1]) only alias tile t-1's buffer,
// whose reads completed (lgkmcnt before MFMA) before the boundary barrier.
// Per-wave vmcnt covers own loads; barrier after wait makes it collective.
// Last tile: the p0 wait becomes vmcnt(0) (Bi has no newer loads behind it).
//
// grid: x = bm (fast, 128), y = bn (8). Blocks sharing an A-panel are 128
// apart in dispatch id -> same id%8 -> same XCD -> A re-reads hit that L2.
__global__ __launch_bounds__(512, 2) void dual_gemm_kernel(
    const short* __restrict__ xb, const short* __restrict__ wrb,
    const short* __restrict__ wib, const float* __restrict__ ls,
    uint32_t* __restrict__ ab, float* __restrict__ Asum,
    float* __restrict__ Esum) {
  __shared__ short lds[2 * 32768];   // 128 KiB

  const int tid  = threadIdx.x;
  const int lane = tid & 63;
  const int wv   = tid >> 6;       // wave 0..7
  const int wm   = wv >> 1;        // wave row 0..3 (4x2 wave grid)
  const int wn   = wv & 1;         // wave col 0..1
  const int c16  = lane & 15;
  const int q    = lane >> 4;      // quad 0..3

  const int bm = blockIdx.x * BM;
  const int bn = blockIdx.y * BN;

  floatx4 accR[4][4], accI[4][4];
  #pragma unroll
  for (int i = 0; i < 4; ++i)
    #pragma unroll
    for (int j = 0; j < 4; ++j) {
      accR[i][j] = (floatx4){0.f,0.f,0.f,0.f};
      accI[i][j] = (floatx4){0.f,0.f,0.f,0.f};
    }

  // staging geometry: one wave-load = 64 lanes x 16B = 8 rows x (8 chunks of
  // 16B). LDS chunk (r, c') holds global k-chunk c = c' ^ (r&7) (XOR swizzle
  // applied on the global source address; LDS dest = wave_base + lane*16).
  const int srow   = lane >> 3;    // 0..7
  const int schunk = lane & 7;

  auto stageA = [&](int buf, int k0, int half) {   // 2 loads: A rows half*16..
    short* dst = lds + buf * 32768;
    #pragma unroll
    for (int i = 0; i < 2; ++i) {
      int l  = half*2 + i;
      int r  = wv*32 + l*8 + srow;
      int cc = schunk ^ (r & 7);
      gload_lds16(xb + (size_t)(bm + r)*K_ + k0 + cc*8,
                  dst + wv*2048 + l*512);
    }
  };
  auto stageB = [&](int buf, int k0, const short* W, int base) {  // 2 loads
    short* dst = lds + buf * 32768 + base;
    #pragma unroll
    for (int l = 0; l < 2; ++l) {
      int r  = wv*16 + l*8 + srow;
      int cc = schunk ^ (r & 7);
      gload_lds16(W + (size_t)(bn + r)*K_ + k0 + cc*8,
                  dst + wv*1024 + l*512);
    }
  };

  // prologue: full tile 0, then counted wait (Bi may stay in flight)
  stageA(0, 0, 0); stageA(0, 0, 1);
  stageB(0, 0, wrb, 16384); stageB(0, 0, wib, 24576);
  asm volatile("s_waitcnt vmcnt(2)" ::: "memory");
  __builtin_amdgcn_s_barrier();

  for (int step = 0; step < NSTEP; ++step) {
    const short* As  = lds + (step & 1) * 32768;
    const short* Brs = As + 16384;
    const short* Bis = As + 24576;
    const int  nb  = (step + 1) & 1;
    const int  nk  = (step + 1) * BK;
    const bool pre = (step + 1 < NSTEP);

    short8 af0[4], af1[4], bf[4];

    // ---- phase 0: R kk0 ----
    #pragma unroll
    for (int f = 0; f < 4; ++f) {
      int m_loc = wm*64 + f*16 + c16;
      af0[f] = *(const short8*)(As  + m_loc*64 + ((q) ^ (m_loc & 7))*8);
      int n_loc = wn*64 + f*16 + c16;
      bf[f]  = *(const short8*)(Brs + n_loc*64 + ((q) ^ (n_loc & 7))*8);
    }
    if (pre) stageA(nb, nk, 0);
    __builtin_amdgcn_s_barrier();
    __builtin_amdgcn_s_setprio(1);
    MFMA_CLUSTER(accR, af0, bf);
    __builtin_amdgcn_s_setprio(0);
    if (pre) asm volatile("s_waitcnt vmcnt(2)" ::: "memory");  // Bi(t) done
    else     asm volatile("s_waitcnt vmcnt(0)" ::: "memory");
    __builtin_amdgcn_s_barrier();

    // ---- phase 1: I kk0 (af reuse) ----
    #pragma unroll
    for (int f = 0; f < 4; ++f) {
      int n_loc = wn*64 + f*16 + c16;
      bf[f] = *(const short8*)(Bis + n_loc*64 + ((q) ^ (n_loc & 7))*8);
    }
    if (pre) stageA(nb, nk, 1);
    __builtin_amdgcn_s_barrier();
    __builtin_amdgcn_s_setprio(1);
    MFMA_CLUSTER(accI, af0, bf);
    __builtin_amdgcn_s_setprio(0);
    __builtin_amdgcn_s_barrier();

    // ---- phase 2: R kk1 ----
    #pragma unroll
    for (int f = 0; f < 4; ++f) {
      int m_loc = wm*64 + f*16 + c16;
      af1[f] = *(const short8*)(As  + m_loc*64 + ((4 + q) ^ (m_loc & 7))*8);
      int n_loc = wn*64 + f*16 + c16;
      bf[f]  = *(const short8*)(Brs + n_loc*64 + ((4 + q) ^ (n_loc & 7))*8);
    }
    if (pre) stageB(nb, nk, wrb, 16384);
    __builtin_amdgcn_s_barrier();
    __builtin_amdgcn_s_setprio(1);
    MFMA_CLUSTER(accR, af1, bf);
    __builtin_amdgcn_s_setprio(0);
    __builtin_amdgcn_s_barrier();

    // ---- phase 3: I kk1 (af reuse) ----
    #pragma unroll
    for (int f = 0; f < 4; ++f) {
      int n_loc = wn*64 + f*16 + c16;
      bf[f] = *(const short8*)(Bis + n_loc*64 + ((4 + q) ^ (n_loc & 7))*8);
    }
    if (pre) stageB(nb, nk, wib, 24576);
    __builtin_amdgcn_s_barrier();
    __builtin_amdgcn_s_setprio(1);
    MFMA_CLUSTER(accI, af1, bf);
    __builtin_amdgcn_s_setprio(0);
    if (pre) asm volatile("s_waitcnt vmcnt(2)" ::: "memory");  // A0/A1/Br(t+1)
    __builtin_amdgcn_s_barrier();   // tile boundary
  }

  // epilogue: C/D layout (m89-verified): col = lane&15, row = quad*4 + reg
  // x re-read in bf16 (b is stored bf16 anyway -> no accuracy loss, half fetch)
  // Fused summary: lane rows within a wave are wm*64 + fm*16 + q*4 + j.
  //   (1) serial fold over j  -> 4-row segment (SA,SE)      [in-lane]
  //   (2) 2x shfl_xor over q  -> 16-row segment             [cross-lane, ordered]
  //   (3) serial fold over fm -> 64-row chunk (WA,WE)       [in-lane]
  // Summary uses the bf16-ROUNDED (la,b) so carries match what scan_final reads.
  const int b_idx = bm >> 12;                    // bm / T_
  const int c2    = ((bm & (T_-1)) >> 6) + wm;   // 64-row chunk index in [0,NC2)
  #pragma unroll
  for (int fn = 0; fn < 4; ++fn) {
    int col = bn + wn*64 + fn*16 + c16;
    float lsv = ls[col];
    float WA = 1.f, WE = 0.f;                    // running chunk (A,E)
    #pragma unroll
    for (int fm = 0; fm < 4; ++fm) {
      float SA = 1.f, SE = 0.f;                  // this lane's 4-row segment
      #pragma unroll
      for (int j = 0; j < 4; ++j) {
        int row = bm + wm*64 + fm*16 + q*4 + j;
        float pr = accR[fm][fn][j];
        float pi = accI[fm][fn][j];
        float rg = 1.f / (1.f + __expf(-pr));
        float ig = 1.f / (1.f + __expf(-pi));
        float la = 8.f * rg * lsv;               // log_a <= 0
        uint32_t xu = (uint32_t)(uint16_t)xb[(size_t)row*K_ + col];
        float xv = __uint_as_float(xu << 16);
        float a2 = __expf(2.f * la);
        float bb = sqrtf(fmaxf(1.f - a2, 0.f)) * ig * xv;
        uint32_t pk = (f2bf(bb) << 16) | f2bf(la);
        ab[(size_t)row*N_ + col] = pk;
        float av  = __expf(__uint_as_float(pk << 16));        // rounded a
        float bbr = __uint_as_float(pk & 0xffff0000u);        // rounded b
        SA *= av;
        SE = fmaf(av, SE, bbr);
      }
      // ordered combine of adjacent 4-row segments across q (lanes 16,32 apart)
      #pragma unroll
      for (int s = 16; s <= 32; s <<= 1) {
        float OA = __shfl_xor(SA, s);
        float OE = __shfl_xor(SE, s);
        SE = (lane & s) ? fmaf(SA, OE, SE)       // self is the later segment
                        : fmaf(OA, SE, OE);      // other is the later segment
        SA *= OA;
      }
      WE = fmaf(SA, WE, SE);                     // append 16-row segment
      WA *= SA;
    }
    if (q == 0) {                                // one writer per col
      int o = (b_idx * NC2 + c2) * D_ + col;
      Asum[o] = WA;
      Esum[o] = WE;
    }
  }
}

// ---------------- Kernel C2: turn (A,E) summaries into per-chunk carries ----
// Overwrites Asum[b,c,d] with carry = h state entering chunk c.
__global__ __launch_bounds__(256) void scan_carry(
    float* __restrict__ Asum, const float* __restrict__ Esum) {
  int b = blockIdx.x >> 2;                       // grid = B_*4 = 32 blocks
  int d = ((blockIdx.x & 3) << 8) + threadIdx.x;
  float carry = 0.f;
  #pragma unroll 8
  for (int c = 0; c < NC2; ++c) {
    int o = (b*NC2 + c)*D_ + d;
    float A = Asum[o], E = Esum[o];
    Asum[o] = carry;
    carry = fmaf(A, carry, E);
  }
}

// ---------------- Kernel D: final scan with precomputed carry, writes h -----
// uint2-vectorized (8 B/lane), TC2=64 chunks -> 1024 blocks (16 waves/CU).
__global__ __launch_bounds__(256) void scan_final(
    uint32_t* __restrict__ out, const float* __restrict__ carry_buf) {
  int blk = blockIdx.x;              // B_ * NC2 * 2 = 1024 blocks
  int dg = blk & 1;                  // D half (in uint2 units)
  int c  = (blk >> 1) & (NC2 - 1);
  int b  = blk >> 7;
  int d2 = (dg << 8) + threadIdx.x;  // uint2 index: covers d = 2*d2, 2*d2+1

  const float2* cb = (const float2*)(carry_buf + (size_t)(b*NC2 + c)*D_);
  float2 hc = cb[d2];
  float h0 = hc.x, h1 = hc.y;

  uint2* p = (uint2*)(out + ((size_t)(b*T_ + c*TC2))*D_) + d2;
  #pragma unroll 4
  for (int t = 0; t < TC2; ++t) {
    size_t o = (size_t)t * (D_/2);
    uint2 v = p[o];                          // packed (log_a, b) x2
    float a0 = __expf(__uint_as_float(v.x << 16));
    h0 = fmaf(a0, h0, __uint_as_float(v.x & 0xffff0000u));
    float a1 = __expf(__uint_as_float(v.y << 16));
    h1 = fmaf(a1, h1, __uint_as_float(v.y & 0xffff0000u));
    uint2 ov; ov.x = __float_as_uint(h0); ov.y = __float_as_uint(h1);
    p[o] = ov;                               // overwrite with h (fp32)
  }
}

extern "C" void kernel_launch(void* const* d_in, const int* in_sizes, int n_in,
                              void* d_out, int out_size, void* d_ws, size_t ws_size,
                              hipStream_t stream) {
  (void)in_sizes; (void)n_in; (void)out_size;
  if (ws_size < WS_NEED) return;   // need ~72 MiB scratch

  const float* x     = (const float*)d_in[0];
  const float* Wr    = (const float*)d_in[1];
  const float* Wi    = (const float*)d_in[2];
  const float* lambd = (const float*)d_in[3];

  char* ws = (char*)d_ws;
  short* xb   = (short*)(ws + XB_OFF);
  short* wrb  = (short*)(ws + WR_OFF);
  short* wib  = (short*)(ws + WI_OFF);
  float* ls   = (float*)(ws + LS_OFF);
  float* Asum = (float*)(ws + ASUM_OFF);
  float* Esum = (float*)(ws + ESUM_OFF);

  uint32_t* ab = (uint32_t*)d_out;   // packed (log_a, b) lives in d_out, then
                                     // scan_final overwrites it with h (fp32)

  convert_kernel<<<4096, 256, 0, stream>>>(x, Wr, Wi, lambd,
                                           (uint2*)xb, (uint2*)wrb, (uint2*)wib, ls);
  dual_gemm_kernel<<<dim3(M_/BM, N_/BN), 512, 0, stream>>>(xb, wrb, wib, ls, ab,
                                                           Asum, Esum);
  scan_carry<<<B_ * 4, 256, 0, stream>>>(Asum, Esum);
  scan_final<<<B_ * NC2 * 2, 256, 0, stream>>>(ab, Asum);
}

// Round 5
// 436.708 us; speedup vs baseline: 1.0385x; 1.0385x over previous
//
#include <hip/hip_runtime.h>
#include <hip/hip_bf16.h>
#include <cstdint>

#define B_   8
#define T_   4096
#define D_   1024
#define M_   (B_*T_)      // 32768
#define K_   D_           // 1024
#define N_   D_           // 1024

#define TC2  64           // scan chunk length (= one wave's row span in GEMM)
#define NC2  (T_/TC2)     // 64 chunks

#define BM   256
#define BN   128
#define BK   64
#define NSTEP (K_/BK)     // 16

typedef __attribute__((ext_vector_type(8))) short  short8;
typedef __attribute__((ext_vector_type(4))) float  floatx4;

// ---- workspace layout (bytes) ----
#define XB_OFF    0ull                                   // x as bf16: 64 MiB
#define WR_OFF    (XB_OFF + (size_t)M_*K_*2)             // W_r bf16: 2 MiB
#define WI_OFF    (WR_OFF + (size_t)N_*K_*2)             // W_i bf16: 2 MiB
#define LS_OFF    (WI_OFF + (size_t)N_*K_*2)             // logsigmoid(lambd): 4 KiB
#define ASUM_OFF  (LS_OFF + (size_t)D_*4)                // chunk prod(a) -> carries: 2 MiB
#define ESUM_OFF  (ASUM_OFF + (size_t)B_*NC2*D_*4)       // chunk h_end: 2 MiB
#define WS_NEED   (ESUM_OFF + (size_t)B_*NC2*D_*4)

__device__ __forceinline__ uint32_t f2bf(float f) {
  uint32_t u = __float_as_uint(f);
  return (u + 0x7fffu + ((u >> 16) & 1u)) >> 16;   // RTNE bf16
}

__device__ __forceinline__ void gload_lds16(const void* g, void* l) {
  __builtin_amdgcn_global_load_lds(
      (const __attribute__((address_space(1))) void*)g,
      (__attribute__((address_space(3))) void*)l, 16, 0, 0);
}

#define MFMA_CLUSTER(ACC, AF, BF)                                        \
  _Pragma("unroll")                                                      \
  for (int fm = 0; fm < 4; ++fm)                                         \
    _Pragma("unroll")                                                    \
    for (int fn = 0; fn < 4; ++fn)                                       \
      ACC[fm][fn] = __builtin_amdgcn_mfma_f32_16x16x32_bf16(             \
          AF[fm], BF[fn], ACC[fm][fn], 0, 0, 0);

// ---------------- Kernel A: fp32 -> bf16 conversion + logsigmoid(lambd) ----
__global__ __launch_bounds__(256) void convert_kernel(
    const float* __restrict__ x, const float* __restrict__ wr,
    const float* __restrict__ wi, const float* __restrict__ lambd,
    uint2* __restrict__ xb, uint2* __restrict__ wrb, uint2* __restrict__ wib,
    float* __restrict__ ls) {
  int gid = blockIdx.x * 256 + threadIdx.x;
  if (gid < D_) {
    float l = lambd[gid];
    // log_sigmoid(l) = min(l,0) - log1p(exp(-|l|)), stable
    ls[gid] = fminf(l, 0.f) - log1pf(__expf(-fabsf(l)));
  }
  const int XQ = M_*K_/4;   // float4 quads in x
  const int WQ = N_*K_/4;   // quads in each W
  int stride = gridDim.x * 256;
  for (int q = gid; q < XQ + 2*WQ; q += stride) {
    const float4* src; uint2* dst; int i;
    if (q < XQ)           { src = (const float4*)x;  dst = xb;  i = q; }
    else if (q < XQ + WQ) { src = (const float4*)wr; dst = wrb; i = q - XQ; }
    else                  { src = (const float4*)wi; dst = wib; i = q - XQ - WQ; }
    float4 v = src[i];
    uint2 o;
    o.x = (f2bf(v.y) << 16) | f2bf(v.x);
    o.y = (f2bf(v.w) << 16) | f2bf(v.z);
    dst[i] = o;
  }
}

// ---------------- Kernel B: dual GEMM, 8-phase counted-vmcnt schedule -------
// BM=256 x BN=128, 8 waves (4x2 grid, per-wave 64x64 output x {R,I}).
// LDS 128 KiB: double-buffered (A 32K | Br 16K | Bi 16K) x 2. 1 block/CU.
//
// GRID SWIZZLE (R4 fix): 1D grid, xg=(bid&7)*16+(bid>>6), yg=(bid>>3)&7
// (bijective, nwg=1024 % 8 == 0). XCD j (ids = j mod 8) hosts 4 A-panels x
// all 8 bn-sharers CONCURRENTLY -> shared A k-window stays in that XCD's L2,
// A fetched from HBM once (was ~4x: the old (x fast, y outer) grid put
// bn-sharers 128 dispatch-slots apart -> panel evicted between rounds).
// This also converts stage loads from ~900-cyc HBM misses to ~200-cyc L2
// hits, which the counted-vmcnt pipeline CAN hide (why R3/R4 were null).
//
// T3+T4 (m194-m201 template): each K-tile = 4 phases of 16 MFMA:
//   p0: R,kk0 (A kk0 + Br kk0)         stage A-half0 of tile t+1
//   p1: I,kk0 (Bi kk0; af reuse)       stage A-half1
//   p2: R,kk1 (A kk1 + Br kk1)         stage Br
//   p3: I,kk1 (Bi kk1; af reuse)       stage Bi
// Counted waits, never a main-loop drain:
//   end p0: vmcnt(2) -> completes Bi(t)        [A-half0(t+1) stays in flight]
//   end p3: vmcnt(2) -> completes A0/A1/Br(t+1) [Bi(t+1) stays in flight]
// Race proof: stage of t+1 writes buf[(t+1)&1] = tile t-1's buffer, whose
// reads completed (lgkmcnt before MFMA) before the boundary barrier.
__global__ __launch_bounds__(512, 2) void dual_gemm_kernel(
    const short* __restrict__ xb, const short* __restrict__ wrb,
    const short* __restrict__ wib, const float* __restrict__ ls,
    uint32_t* __restrict__ ab, float* __restrict__ Asum,
    float* __restrict__ Esum) {
  __shared__ short lds[2 * 32768];   // 128 KiB

  const int tid  = threadIdx.x;
  const int lane = tid & 63;
  const int wv   = tid >> 6;       // wave 0..7
  const int wm   = wv >> 1;        // wave row 0..3 (4x2 wave grid)
  const int wn   = wv & 1;         // wave col 0..1
  const int c16  = lane & 15;
  const int q    = lane >> 4;      // quad 0..3

  const int bid = blockIdx.x;                    // 0..1023
  const int xg  = ((bid & 7) << 4) | (bid >> 6); // 0..127  (bm tile)
  const int yg  = (bid >> 3) & 7;                // 0..7    (bn tile)
  const int bm  = xg * BM;
  const int bn  = yg * BN;

  floatx4 accR[4][4], accI[4][4];
  #pragma unroll
  for (int i = 0; i < 4; ++i)
    #pragma unroll
    for (int j = 0; j < 4; ++j) {
      accR[i][j] = (floatx4){0.f,0.f,0.f,0.f};
      accI[i][j] = (floatx4){0.f,0.f,0.f,0.f};
    }

  // staging geometry: one wave-load = 64 lanes x 16B = 8 rows x (8 chunks of
  // 16B). LDS chunk (r, c') holds global k-chunk c = c' ^ (r&7) (XOR swizzle
  // applied on the global source address; LDS dest = wave_base + lane*16).
  const int srow   = lane >> 3;    // 0..7
  const int schunk = lane & 7;

  auto stageA = [&](int buf, int k0, int half) {   // 2 loads: A rows half*16..
    short* dst = lds + buf * 32768;
    #pragma unroll
    for (int i = 0; i < 2; ++i) {
      int l  = half*2 + i;
      int r  = wv*32 + l*8 + srow;
      int cc = schunk ^ (r & 7);
      gload_lds16(xb + (size_t)(bm + r)*K_ + k0 + cc*8,
                  dst + wv*2048 + l*512);
    }
  };
  auto stageB = [&](int buf, int k0, const short* W, int base) {  // 2 loads
    short* dst = lds + buf * 32768 + base;
    #pragma unroll
    for (int l = 0; l < 2; ++l) {
      int r  = wv*16 + l*8 + srow;
      int cc = schunk ^ (r & 7);
      gload_lds16(W + (size_t)(bn + r)*K_ + k0 + cc*8,
                  dst + wv*1024 + l*512);
    }
  };

  // prologue: full tile 0, then counted wait (Bi may stay in flight)
  stageA(0, 0, 0); stageA(0, 0, 1);
  stageB(0, 0, wrb, 16384); stageB(0, 0, wib, 24576);
  asm volatile("s_waitcnt vmcnt(2)" ::: "memory");
  __builtin_amdgcn_s_barrier();

  for (int step = 0; step < NSTEP; ++step) {
    const short* As  = lds + (step & 1) * 32768;
    const short* Brs = As + 16384;
    const short* Bis = As + 24576;
    const int  nb  = (step + 1) & 1;
    const int  nk  = (step + 1) * BK;
    const bool pre = (step + 1 < NSTEP);

    short8 af0[4], af1[4], bf[4];

    // ---- phase 0: R kk0 ----
    #pragma unroll
    for (int f = 0; f < 4; ++f) {
      int m_loc = wm*64 + f*16 + c16;
      af0[f] = *(const short8*)(As  + m_loc*64 + ((q) ^ (m_loc & 7))*8);
      int n_loc = wn*64 + f*16 + c16;
      bf[f]  = *(const short8*)(Brs + n_loc*64 + ((q) ^ (n_loc & 7))*8);
    }
    if (pre) stageA(nb, nk, 0);
    __builtin_amdgcn_s_barrier();
    __builtin_amdgcn_s_setprio(1);
    MFMA_CLUSTER(accR, af0, bf);
    __builtin_amdgcn_s_setprio(0);
    if (pre) asm volatile("s_waitcnt vmcnt(2)" ::: "memory");  // Bi(t) done
    else     asm volatile("s_waitcnt vmcnt(0)" ::: "memory");
    __builtin_amdgcn_s_barrier();

    // ---- phase 1: I kk0 (af reuse) ----
    #pragma unroll
    for (int f = 0; f < 4; ++f) {
      int n_loc = wn*64 + f*16 + c16;
      bf[f] = *(const short8*)(Bis + n_loc*64 + ((q) ^ (n_loc & 7))*8);
    }
    if (pre) stageA(nb, nk, 1);
    __builtin_amdgcn_s_barrier();
    __builtin_amdgcn_s_setprio(1);
    MFMA_CLUSTER(accI, af0, bf);
    __builtin_amdgcn_s_setprio(0);
    __builtin_amdgcn_s_barrier();

    // ---- phase 2: R kk1 ----
    #pragma unroll
    for (int f = 0; f < 4; ++f) {
      int m_loc = wm*64 + f*16 + c16;
      af1[f] = *(const short8*)(As  + m_loc*64 + ((4 + q) ^ (m_loc & 7))*8);
      int n_loc = wn*64 + f*16 + c16;
      bf[f]  = *(const short8*)(Brs + n_loc*64 + ((4 + q) ^ (n_loc & 7))*8);
    }
    if (pre) stageB(nb, nk, wrb, 16384);
    __builtin_amdgcn_s_barrier();
    __builtin_amdgcn_s_setprio(1);
    MFMA_CLUSTER(accR, af1, bf);
    __builtin_amdgcn_s_setprio(0);
    __builtin_amdgcn_s_barrier();

    // ---- phase 3: I kk1 (af reuse) ----
    #pragma unroll
    for (int f = 0; f < 4; ++f) {
      int n_loc = wn*64 + f*16 + c16;
      bf[f] = *(const short8*)(Bis + n_loc*64 + ((4 + q) ^ (n_loc & 7))*8);
    }
    if (pre) stageB(nb, nk, wib, 24576);
    __builtin_amdgcn_s_barrier();
    __builtin_amdgcn_s_setprio(1);
    MFMA_CLUSTER(accI, af1, bf);
    __builtin_amdgcn_s_setprio(0);
    if (pre) asm volatile("s_waitcnt vmcnt(2)" ::: "memory");  // A0/A1/Br(t+1)
    __builtin_amdgcn_s_barrier();   // tile boundary
  }

  // epilogue: C/D layout (m89-verified): col = lane&15, row = quad*4 + reg
  // x re-read in bf16 (part of this XCD's L2-resident A-panel post-swizzle)
  // Fused summary: lane rows within a wave are wm*64 + fm*16 + q*4 + j.
  //   (1) serial fold over j  -> 4-row segment (SA,SE)      [in-lane]
  //   (2) 2x shfl_xor over q  -> 16-row segment             [cross-lane, ordered]
  //   (3) serial fold over fm -> 64-row chunk (WA,WE)       [in-lane]
  // Summary uses the bf16-ROUNDED (la,b) so carries match what scan_final reads.
  const int b_idx = bm >> 12;                    // bm / T_
  const int c2    = ((bm & (T_-1)) >> 6) + wm;   // 64-row chunk index in [0,NC2)
  #pragma unroll
  for (int fn = 0; fn < 4; ++fn) {
    int col = bn + wn*64 + fn*16 + c16;
    float lsv = ls[col];
    float WA = 1.f, WE = 0.f;                    // running chunk (A,E)
    #pragma unroll
    for (int fm = 0; fm < 4; ++fm) {
      float SA = 1.f, SE = 0.f;                  // this lane's 4-row segment
      #pragma unroll
      for (int j = 0; j < 4; ++j) {
        int row = bm + wm*64 + fm*16 + q*4 + j;
        float pr = accR[fm][fn][j];
        float pi = accI[fm][fn][j];
        float rg = 1.f / (1.f + __expf(-pr));
        float ig = 1.f / (1.f + __expf(-pi));
        float la = 8.f * rg * lsv;               // log_a <= 0
        uint32_t xu = (uint32_t)(uint16_t)xb[(size_t)row*K_ + col];
        float xv = __uint_as_float(xu << 16);
        float a2 = __expf(2.f * la);
        float bb = sqrtf(fmaxf(1.f - a2, 0.f)) * ig * xv;
        uint32_t pk = (f2bf(bb) << 16) | f2bf(la);
        ab[(size_t)row*N_ + col] = pk;
        float av  = __expf(__uint_as_float(pk << 16));        // rounded a
        float bbr = __uint_as_float(pk & 0xffff0000u);        // rounded b
        SA *= av;
        SE = fmaf(av, SE, bbr);
      }
      // ordered combine of adjacent 4-row segments across q (lanes 16,32 apart)
      #pragma unroll
      for (int s = 16; s <= 32; s <<= 1) {
        float OA = __shfl_xor(SA, s);
        float OE = __shfl_xor(SE, s);
        SE = (lane & s) ? fmaf(SA, OE, SE)       // self is the later segment
                        : fmaf(OA, SE, OE);      // other is the later segment
        SA *= OA;
      }
      WE = fmaf(SA, WE, SE);                     // append 16-row segment
      WA *= SA;
    }
    if (q == 0) {                                // one writer per col
      int o = (b_idx * NC2 + c2) * D_ + col;
      Asum[o] = WA;
      Esum[o] = WE;
    }
  }
}

// ---------------- Kernel C2: turn (A,E) summaries into per-chunk carries ----
// Overwrites Asum[b,c,d] with carry = h state entering chunk c.
__global__ __launch_bounds__(256) void scan_carry(
    float* __restrict__ Asum, const float* __restrict__ Esum) {
  int b = blockIdx.x >> 2;                       // grid = B_*4 = 32 blocks
  int d = ((blockIdx.x & 3) << 8) + threadIdx.x;
  float carry = 0.f;
  #pragma unroll 8
  for (int c = 0; c < NC2; ++c) {
    int o = (b*NC2 + c)*D_ + d;
    float A = Asum[o], E = Esum[o];
    Asum[o] = carry;
    carry = fmaf(A, carry, E);
  }
}

// ---------------- Kernel D: final scan with precomputed carry, writes h -----
// uint2-vectorized (8 B/lane), TC2=64 chunks -> 1024 blocks (16 waves/CU).
__global__ __launch_bounds__(256) void scan_final(
    uint32_t* __restrict__ out, const float* __restrict__ carry_buf) {
  int blk = blockIdx.x;              // B_ * NC2 * 2 = 1024 blocks
  int dg = blk & 1;                  // D half (in uint2 units)
  int c  = (blk >> 1) & (NC2 - 1);
  int b  = blk >> 7;
  int d2 = (dg << 8) + threadIdx.x;  // uint2 index: covers d = 2*d2, 2*d2+1

  const float2* cb = (const float2*)(carry_buf + (size_t)(b*NC2 + c)*D_);
  float2 hc = cb[d2];
  float h0 = hc.x, h1 = hc.y;

  uint2* p = (uint2*)(out + ((size_t)(b*T_ + c*TC2))*D_) + d2;
  #pragma unroll 4
  for (int t = 0; t < TC2; ++t) {
    size_t o = (size_t)t * (D_/2);
    uint2 v = p[o];                          // packed (log_a, b) x2
    float a0 = __expf(__uint_as_float(v.x << 16));
    h0 = fmaf(a0, h0, __uint_as_float(v.x & 0xffff0000u));
    float a1 = __expf(__uint_as_float(v.y << 16));
    h1 = fmaf(a1, h1, __uint_as_float(v.y & 0xffff0000u));
    uint2 ov; ov.x = __float_as_uint(h0); ov.y = __float_as_uint(h1);
    p[o] = ov;                               // overwrite with h (fp32)
  }
}

extern "C" void kernel_launch(void* const* d_in, const int* in_sizes, int n_in,
                              void* d_out, int out_size, void* d_ws, size_t ws_size,
                              hipStream_t stream) {
  (void)in_sizes; (void)n_in; (void)out_size;
  if (ws_size < WS_NEED) return;   // need ~72 MiB scratch

  const float* x     = (const float*)d_in[0];
  const float* Wr    = (const float*)d_in[1];
  const float* Wi    = (const float*)d_in[2];
  const float* lambd = (const float*)d_in[3];

  char* ws = (char*)d_ws;
  short* xb   = (short*)(ws + XB_OFF);
  short* wrb  = (short*)(ws + WR_OFF);
  short* wib  = (short*)(ws + WI_OFF);
  float* ls   = (float*)(ws + LS_OFF);
  float* Asum = (float*)(ws + ASUM_OFF);
  float* Esum = (float*)(ws + ESUM_OFF);

  uint32_t* ab = (uint32_t*)d_out;   // packed (log_a, b) lives in d_out, then
                                     // scan_final overwrites it with h (fp32)

  convert_kernel<<<4096, 256, 0, stream>>>(x, Wr, Wi, lambd,
                                           (uint2*)xb, (uint2*)wrb, (uint2*)wib, ls);
  dual_gemm_kernel<<<(M_/BM) * (N_/BN), 512, 0, stream>>>(xb, wrb, wib, ls, ab,
                                                          Asum, Esum);
  scan_carry<<<B_ * 4, 256, 0, stream>>>(Asum, Esum);
  scan_final<<<B_ * NC2 * 2, 256, 0, stream>>>(ab, Asum);
}